// Round 10
// baseline (185.550 us; speedup 1.0000x reference)
//
#include <hip/hip_runtime.h>

#define N_HID 128
#define CAP   32          // bucket slots per node = exactly one 64B line (ushort)
#define OVF_CAP 8192
#define NSLICE 8
#define PBLK   256        // fill-grid size for K1's housekeeping blocks

typedef short bf16x8 __attribute__((ext_vector_type(8)));
typedef float f32x4  __attribute__((ext_vector_type(4)));

// round-to-nearest-even f32 -> bf16 bits
static __device__ __forceinline__ unsigned short f2bf(float f)
{
    unsigned int u = __float_as_uint(f);
    u = (u + 0x7fffu + ((u >> 16) & 1u)) >> 16;
    return (unsigned short)u;
}
static __device__ __forceinline__ unsigned int pack2(float a, float b)
{
    return (unsigned int)f2bf(a) | ((unsigned int)f2bf(b) << 16);
}
// bf16 pair unpack: low half = x<<16, high half = x & 0xffff0000 (1 VALU each)
static __device__ __forceinline__ float lo_f(unsigned int x)
{
    return __uint_as_float(x << 16);
}
static __device__ __forceinline__ float hi_f(unsigned int x)
{
    return __uint_as_float(x & 0xffff0000u);
}

// ---------------------------------------------------------------------------
// K1: blocks [0,PBLK) = zero cnt/ovfn + SENTINEL-FILL bucket (all slots ->
// index n, the zero row). The edge-count pass is GONE (no part/blockCnt in
// the direct-scatter pipeline).
// Blocks [PBLK,PBLK+16) = weight fragmentize (We 0-7, Ws 8-15).
// Blocks [PBLK+16, ...) = cast h f32 -> hbf bf16 row-major, PLUS row n = 0
// (sentinel row read by padded gather slots).
// ---------------------------------------------------------------------------
__global__ __launch_bounds__(256) void fill_fragw_cast(
    int* __restrict__ cnt, int* __restrict__ ovfn, int n,
    const float* __restrict__ We, const float* __restrict__ Ws,
    unsigned short* __restrict__ Be, unsigned short* __restrict__ Bs,
    const float* __restrict__ h, unsigned short* __restrict__ hbf, int total,
    unsigned int* __restrict__ bucket32, unsigned int sent2)
{
    int t = threadIdx.x, b = blockIdx.x;

    if (b >= PBLK + 16) {   // ---- cast h -> hbf (+ zero sentinel row n) ----
        int idx = (b - PBLK - 16) * 2048 + t * 8;
        if (idx + 8 <= total) {
            float4 v0 = *(const float4*)&h[idx];
            float4 v1 = *(const float4*)&h[idx + 4];
            uint4 pk;
            pk.x = pack2(v0.x, v0.y);
            pk.y = pack2(v0.z, v0.w);
            pk.z = pack2(v1.x, v1.y);
            pk.w = pack2(v1.z, v1.w);
            *(uint4*)&hbf[idx] = pk;
        } else if (idx + 8 <= total + N_HID) {   // sentinel row = zeros
            uint4 z = {0u, 0u, 0u, 0u};
            *(uint4*)&hbf[idx] = z;
        }
        return;
    }

    if (b >= PBLK) {   // ---- weight fragmentize ----
        int bb = b - PBLK;
        const float* srcw = (bb < 8) ? We : Ws;
        unsigned short* dstF = (bb < 8) ? Be : Bs;
        int rt = bb & 7;
        int kc = t >> 6, l = t & 63, m = l & 15, q = l >> 4;
        const float* p = &srcw[(size_t)(rt * 16 + m) * N_HID + kc * 32 + q * 8];
        float4 v0 = *(const float4*)p;
        float4 v1 = *(const float4*)(p + 4);
        uint4 pk;
        pk.x = pack2(v0.x, v0.y);
        pk.y = pack2(v0.z, v0.w);
        pk.z = pack2(v1.x, v1.y);
        pk.w = pack2(v1.z, v1.w);
        *(uint4*)&dstF[(size_t)rt * 2048 + kc * 512 + l * 8] = pk;
        return;
    }

    // ---- zero cnt/ovfn, sentinel-fill bucket ----
    for (int i = b * 256 + t; i < n; i += PBLK * 256) cnt[i] = 0;
    {
        const int nb32 = n * (CAP / 2);          // bucket u32 count
        for (int i = b * 256 + t; i < nb32; i += PBLK * 256) bucket32[i] = sent2;
    }
    if (b == 0 && t == 0) *ovfn = 0;
}

// ---------------------------------------------------------------------------
// K2 (direct bucket scatter — replaces part_scan_scatter + bucket_scatter2):
// grid-stride over edges; one global atomic on cnt[d] + one 2B bucket store
// per edge. No part[] round-trip, no per-slice machinery. 800k atomics over
// 50k counters (~16/counter) pipeline across 524k threads; cross-XCD
// coherence tax is the A/B under test vs the R8 two-hop design.
// ---------------------------------------------------------------------------
__global__ __launch_bounds__(256) void bucket_scatter_direct(
    const int* __restrict__ src, const int* __restrict__ dst,
    int* __restrict__ cnt,
    unsigned short* __restrict__ bucket,
    int* __restrict__ ovfn,
    long long* __restrict__ ovf,
    int E)
{
    const int stride = (int)(gridDim.x * 256);
    for (int e = (int)(blockIdx.x * 256 + threadIdx.x); e < E; e += stride) {
        int d = dst[e];
        int s = src[e];
        int c = atomicAdd(&cnt[d], 1);
        if (c < CAP) {
            bucket[(size_t)d * CAP + c] = (unsigned short)s;
        } else {
            int o = atomicAdd(ovfn, 1);
            if (o < OVF_CAP) ovf[o] = ((long long)d << 32) | (unsigned int)s;
        }
    }
}

// ---------------------------------------------------------------------------
// K3 (fused gather_mean + gemm) — byte-exact R8/R5-design (best measured:
// 172.3 total). One 16-row tile per block, 256 threads = 4 waves, 4
// nodes/wave. Scalar addressing (node/cnt/bucket wave-uniform -> s_load),
// full-wave coalesced rows (lane owns column pair {2l,2l+1}, no cross-lane
// reduce), 16-deep load batches, sentinel-padded buckets (index n = zero
// row) -> branchless batch 0, single wave-uniform deg>16 skip for batch 1.
// Means packed to LDS [16][68] u32; GEMM: wave w -> column tiles 2w, 2w+1.
// (blockIdx&7 tile mapping retained from R8 — harmless without affinity.)
// ---------------------------------------------------------------------------
__global__ __launch_bounds__(256) void gather_gemm(
    const int* __restrict__ cnt,
    const unsigned short* __restrict__ bucket,
    const int* __restrict__ ovfn,
    const long long* __restrict__ ovf,
    const unsigned short* __restrict__ hbf,
    const unsigned short* __restrict__ Be,
    const unsigned short* __restrict__ Bsf,
    const float* __restrict__ bias,
    float* __restrict__ out,
    int n, int nrt)
{
    __shared__ __align__(16) unsigned int wl[16 * 68];   // 4352 B

    const int t    = threadIdx.x;
    const int lane = t & 63;
    const int widu = __builtin_amdgcn_readfirstlane(t >> 6);   // uniform wave id
    const int slice = blockIdx.x & 7;
    const int g     = blockIdx.x >> 3;
    const int tLo = (int)(((long long)slice * nrt) >> 3);
    const int tHi = (int)(((long long)(slice + 1) * nrt) >> 3);
    const int tile = tLo + g;
    if (tile >= tHi) return;          // uniform across block

    const unsigned int* h32 = (const unsigned int*)hbf;   // 64 uints per row

    // ---- gather phase: 4 nodes per wave, full-wave coalesced rows ----
#pragma unroll
    for (int k = 0; k < 4; ++k) {
        const int mm   = widu * 4 + k;
        const int node = tile * 16 + mm;
        float ax = 0.f, ay = 0.f;
        int deg = 0;
        if (node < n) {                               // wave-uniform
            deg = cnt[node];                          // scalar load
            const unsigned short* bk = &bucket[(size_t)node * CAP];

            // batch 0: slots 0..15 (sentinel-padded -> always safe)
            {
                unsigned int v[16];
#pragma unroll
                for (int i = 0; i < 16; ++i) {
                    const unsigned int r = bk[i];     // SALU extract from s_load
                    v[i] = h32[(size_t)r * 64 + lane];
                }
#pragma unroll
                for (int i = 0; i < 16; ++i) {
                    ax += lo_f(v[i]); ay += hi_f(v[i]);
                }
            }
            // batch 1: slots 16..31 (wave-uniform skip)
            if (deg > 16) {
                unsigned int v[16];
#pragma unroll
                for (int i = 0; i < 16; ++i) {
                    const unsigned int r = bk[16 + i];
                    v[i] = h32[(size_t)r * 64 + lane];
                }
#pragma unroll
                for (int i = 0; i < 16; ++i) {
                    ax += lo_f(v[i]); ay += hi_f(v[i]);
                }
            }

            if (deg > CAP) {             // exact fallback; few nodes hit it
                int no = *ovfn; if (no > OVF_CAP) no = OVF_CAP;
                for (int o = 0; o < no; ++o) {
                    long long pk = ovf[o];
                    if ((int)(pk >> 32) == node) {
                        unsigned int x = h32[(size_t)(unsigned int)pk * 64 + lane];
                        ax += lo_f(x); ay += hi_f(x);
                    }
                }
            }
        }

        float sc = deg > 0 ? 1.0f / (float)deg : 0.f;
        // lane holds cols {2*lane, 2*lane+1}: word `lane` of node mm's row
        wl[mm * 68 + lane] = pack2(ax * sc, ay * sc);
    }
    __syncthreads();

    // ---- GEMM phase: 4 waves split the 8 column tiles (2 each) ----
    const int rr = lane & 15, qq = lane >> 4;
    const int row0 = tile * 16;

    bf16x8 ah[4], ag[4];
#pragma unroll
    for (int kc = 0; kc < 4; ++kc) {
        int gr = row0 + rr; if (gr > n - 1) gr = n - 1;
        ah[kc] = *(const bf16x8*)&hbf[(size_t)gr * N_HID + kc * 32 + qq * 8];
        // A-frag: row rr, u32 cols kc*16 + qq*4 .. +3 (padded stride 68)
        ag[kc] = *(const bf16x8*)&wl[rr * 68 + kc * 16 + qq * 4];
    }

    const int colb = lane & 15;
    const int rq   = (lane >> 4) * 4;

#pragma unroll
    for (int cti = 0; cti < 2; ++cti) {
        int ct = widu * 2 + cti;
        const bf16x8* BpS = (const bf16x8*)(Bsf + (size_t)ct * 2048);
        const bf16x8* BpE = (const bf16x8*)(Be  + (size_t)ct * 2048);
        f32x4 acc = {0.f, 0.f, 0.f, 0.f};
        acc = __builtin_amdgcn_mfma_f32_16x16x32_bf16(ah[0], BpS[lane],       acc, 0, 0, 0);
        acc = __builtin_amdgcn_mfma_f32_16x16x32_bf16(ah[1], BpS[64 + lane],  acc, 0, 0, 0);
        acc = __builtin_amdgcn_mfma_f32_16x16x32_bf16(ah[2], BpS[128 + lane], acc, 0, 0, 0);
        acc = __builtin_amdgcn_mfma_f32_16x16x32_bf16(ah[3], BpS[192 + lane], acc, 0, 0, 0);
        acc = __builtin_amdgcn_mfma_f32_16x16x32_bf16(ag[0], BpE[lane],       acc, 0, 0, 0);
        acc = __builtin_amdgcn_mfma_f32_16x16x32_bf16(ag[1], BpE[64 + lane],  acc, 0, 0, 0);
        acc = __builtin_amdgcn_mfma_f32_16x16x32_bf16(ag[2], BpE[128 + lane], acc, 0, 0, 0);
        acc = __builtin_amdgcn_mfma_f32_16x16x32_bf16(ag[3], BpE[192 + lane], acc, 0, 0, 0);

        int col = ct * 16 + colb;
        float bv = bias[col];
#pragma unroll
        for (int r = 0; r < 4; ++r) {
            int row = row0 + rq + r;
            if (row < n) out[(size_t)row * N_HID + col] = fmaxf(acc[r] + bv, 0.f);
        }
    }
}

// ---------------------------------------------------------------------------
extern "C" void kernel_launch(void* const* d_in, const int* in_sizes, int n_in,
                              void* d_out, int out_size, void* d_ws, size_t ws_size,
                              hipStream_t stream)
{
    const float* h   = (const float*)d_in[0];
    const int*   src = (const int*)d_in[1];
    const int*   dst = (const int*)d_in[2];
    const float* We  = (const float*)d_in[3];
    const float* Ws  = (const float*)d_in[4];
    const float* bs  = (const float*)d_in[5];
    float*       out = (float*)d_out;

    const int n   = in_sizes[0] / N_HID;    // 50000
    const int E   = in_sizes[1];            // 800000
    const int nrt = (n + 15) / 16;          // 3125 row tiles
    const int total = n * N_HID;

    // workspace (~17 MB of the 256 MiB d_ws)
    unsigned short* hbf  = (unsigned short*)d_ws;             // (n+1)*128 bf16 (row n = zero sentinel)
    unsigned short* bucket = hbf + (size_t)(n + 1) * N_HID;   // n*CAP ushort (3.2 MB)
    unsigned short* Be  = bucket + (size_t)n * CAP;           // 8*2048
    unsigned short* Bs  = Be + 8 * 2048;                      // 8*2048
    int*  cnt  = (int*)(Bs + 8 * 2048);                       // n
    int*  ovfn = cnt + n;                                     // 1 (+pad)
    long long* ovf = (long long*)(ovfn + 8);                  // OVF_CAP

    const unsigned int sent2 = (unsigned int)n | ((unsigned int)n << 16);
    const int castBlocks = (total + N_HID + 2047) / 2048;     // covers rows 0..n

    // fused gather+gemm grid: one tile per block (mapping kept from R8)
    const int maxTilesPerSlice = (nrt + NSLICE - 1) / NSLICE; // 391
    const int ggGrid = NSLICE * maxTilesPerSlice;             // 3128

    fill_fragw_cast<<<PBLK + 16 + castBlocks, 256, 0, stream>>>(
        cnt, ovfn, n, We, Ws, Be, Bs, h, hbf, total,
        (unsigned int*)bucket, sent2);
    bucket_scatter_direct<<<2048, 256, 0, stream>>>(src, dst, cnt, bucket,
                                                    ovfn, ovf, E);
    gather_gemm<<<ggGrid, 256, 0, stream>>>(cnt, bucket, ovfn, ovf,
                                            hbf, Be, Bs, bs, out, n, nrt);
}

// Round 11
// 170.658 us; speedup vs baseline: 1.0873x; 1.0873x over previous
//
#include <hip/hip_runtime.h>

#define N_HID 128
#define CAP   32          // bucket slots per node = exactly one 64B line (ushort)
#define OVF_CAP 8192
#define NSLICE 8
#define PBLK   256        // partition grid size (scan runs per-block inside K3)

typedef short bf16x8 __attribute__((ext_vector_type(8)));
typedef float f32x4  __attribute__((ext_vector_type(4)));

// round-to-nearest-even f32 -> bf16 bits
static __device__ __forceinline__ unsigned short f2bf(float f)
{
    unsigned int u = __float_as_uint(f);
    u = (u + 0x7fffu + ((u >> 16) & 1u)) >> 16;
    return (unsigned short)u;
}
static __device__ __forceinline__ unsigned int pack2(float a, float b)
{
    return (unsigned int)f2bf(a) | ((unsigned int)f2bf(b) << 16);
}
// bf16 pair unpack: low half = x<<16, high half = x & 0xffff0000 (1 VALU each)
static __device__ __forceinline__ float lo_f(unsigned int x)
{
    return __uint_as_float(x << 16);
}
static __device__ __forceinline__ float hi_f(unsigned int x)
{
    return __uint_as_float(x & 0xffff0000u);
}
// slice map: ANY deterministic d->[0,8) works as long as count & scatter use
// the IDENTICAL expression.
static __device__ __forceinline__ int slice_of(int d, float sln)
{
    int sl = (int)((float)d * sln);
    return sl > NSLICE - 1 ? NSLICE - 1 : sl;
}

// ---------------------------------------------------------------------------
// K1: blocks [0,PBLK) = per-block per-slice edge counts (no atomics) + zero
// cnt/ovfn + SENTINEL-FILL bucket (all slots -> index n, the zero row).
// Blocks [PBLK,PBLK+16) = weight fragmentize (We 0-7, Ws 8-15).
// Blocks [PBLK+16, ...) = cast h f32 -> hbf bf16 row-major, PLUS row n = 0
// (sentinel row read by padded gather slots).
// ---------------------------------------------------------------------------
__global__ __launch_bounds__(256) void count_fragw_cast(
    const int* __restrict__ dst, int* __restrict__ blockCnt,
    int* __restrict__ cnt, int* __restrict__ ovfn, int E, int n, float sln,
    const float* __restrict__ We, const float* __restrict__ Ws,
    unsigned short* __restrict__ Be, unsigned short* __restrict__ Bs,
    const float* __restrict__ h, unsigned short* __restrict__ hbf, int total,
    unsigned int* __restrict__ bucket32, unsigned int sent2)
{
    int t = threadIdx.x, b = blockIdx.x;

    if (b >= PBLK + 16) {   // ---- cast h -> hbf (+ zero sentinel row n) ----
        int idx = (b - PBLK - 16) * 2048 + t * 8;
        if (idx + 8 <= total) {
            float4 v0 = *(const float4*)&h[idx];
            float4 v1 = *(const float4*)&h[idx + 4];
            uint4 pk;
            pk.x = pack2(v0.x, v0.y);
            pk.y = pack2(v0.z, v0.w);
            pk.z = pack2(v1.x, v1.y);
            pk.w = pack2(v1.z, v1.w);
            *(uint4*)&hbf[idx] = pk;
        } else if (idx + 8 <= total + N_HID) {   // sentinel row = zeros
            uint4 z = {0u, 0u, 0u, 0u};
            *(uint4*)&hbf[idx] = z;
        }
        return;
    }

    if (b >= PBLK) {   // ---- weight fragmentize ----
        int bb = b - PBLK;
        const float* srcw = (bb < 8) ? We : Ws;
        unsigned short* dstF = (bb < 8) ? Be : Bs;
        int rt = bb & 7;
        int kc = t >> 6, l = t & 63, m = l & 15, q = l >> 4;
        const float* p = &srcw[(size_t)(rt * 16 + m) * N_HID + kc * 32 + q * 8];
        float4 v0 = *(const float4*)p;
        float4 v1 = *(const float4*)(p + 4);
        uint4 pk;
        pk.x = pack2(v0.x, v0.y);
        pk.y = pack2(v0.z, v0.w);
        pk.z = pack2(v1.x, v1.y);
        pk.w = pack2(v1.z, v1.w);
        *(uint4*)&dstF[(size_t)rt * 2048 + kc * 512 + l * 8] = pk;
        return;
    }

    // ---- zero cnt/ovfn, sentinel-fill bucket, edge slice counts ----
    for (int i = b * 256 + t; i < n; i += PBLK * 256) cnt[i] = 0;
    {
        const int nb32 = n * (CAP / 2);          // bucket u32 count
        for (int i = b * 256 + t; i < nb32; i += PBLK * 256) bucket32[i] = sent2;
    }
    if (b == 0 && t == 0) *ovfn = 0;

    int c[NSLICE];
#pragma unroll
    for (int s = 0; s < NSLICE; ++s) c[s] = 0;

    for (int e = b * 256 + t; e < E; e += PBLK * 256) {
        int sl = slice_of(dst[e], sln);
#pragma unroll
        for (int s = 0; s < NSLICE; ++s) c[s] += (sl == s);
    }

    __shared__ int red[NSLICE * 4];
    int lane = t & 63, wid = t >> 6;
#pragma unroll
    for (int s = 0; s < NSLICE; ++s) {
        int v = c[s];
#pragma unroll
        for (int off = 32; off; off >>= 1) v += __shfl_down(v, off);
        if (lane == 0) red[s * 4 + wid] = v;
    }
    __syncthreads();
    if (t < NSLICE)
        blockCnt[t * PBLK + b] = red[t*4+0] + red[t*4+1] + red[t*4+2] + red[t*4+3];
}

// ---------------------------------------------------------------------------
// K3 (merged K2+K3): every block REDUNDANTLY scans the PBLK*NSLICE counts
// (8 KB, L2-resident — identical code to the old 1-block part_scan, ~2 µs,
// fully parallel across blocks), keeps the result in LDS, picks out its own
// 8 per-slice bases, then scatters edges into dense per-slice queues using
// LDS atomics. Block 0 also publishes sbase[9] for K4. Saves the separate
// scan launch + its gap. Packed u32 (d<<16)|s (n<=65536).
// ---------------------------------------------------------------------------
__global__ __launch_bounds__(256) void part_scan_scatter(
    const int* __restrict__ blockCnt,
    int* __restrict__ sbase,
    const int* __restrict__ src, const int* __restrict__ dst,
    unsigned int* __restrict__ part,
    int E, int n, float sln)
{
    __shared__ int wsm[4];
    __shared__ int lbase[PBLK * NSLICE];   // 8 KB
    __shared__ int cur[NSLICE];
    int t = threadIdx.x, lane = t & 63, wid = t >> 6;
    int v[8]; int s = 0;
#pragma unroll
    for (int i = 0; i < 8; ++i) { v[i] = blockCnt[t * 8 + i]; s += v[i]; }
    int val = s;
#pragma unroll
    for (int off = 1; off < 64; off <<= 1) {
        int y = __shfl_up(val, off);
        if (lane >= off) val += y;
    }
    if (lane == 63) wsm[wid] = val;
    __syncthreads();
    if (t == 0) { int a = 0; for (int w = 0; w < 4; ++w) { int tmp = wsm[w]; wsm[w] = a; a += tmp; } }
    __syncthreads();
    int excl = wsm[wid] + val - s;
#pragma unroll
    for (int i = 0; i < 8; ++i) { int tv = v[i]; lbase[t * 8 + i] = excl; excl += tv; }
    __syncthreads();

    const int b = blockIdx.x;
    if (t < NSLICE) cur[t] = lbase[t * PBLK + b];
    if (b == 0) {                         // publish slice bases for K4
        if (t < NSLICE) sbase[t] = lbase[t * PBLK];
        if (t == 0)     sbase[NSLICE] = E;
    }
    __syncthreads();

    for (int e = b * 256 + t; e < E; e += PBLK * 256) {
        int d = dst[e], sv = src[e];
        int sl  = slice_of(d, sln);
        int pos = atomicAdd(&cur[sl], 1);
        part[pos] = ((unsigned int)d << 16) | (unsigned int)sv;
    }
}

// ---------------------------------------------------------------------------
// K4: bucket scatter over DENSE per-slice lists. slice = blockIdx&7
// (XCD-affine under round-robin dispatch) -> cnt/bucket lines written from
// ~one XCD. ushort entries, CAP=32 -> one 64B line per node.
// Grid 2048 (256 blocks/slice) to shrink the straggler tail.
// (R9's direct-scatter A/B proved this affinity is worth ~3x on the atomic
// phase: direct device-scope atomics from all 8 XCDs ran 63-69 µs.)
// ---------------------------------------------------------------------------
__global__ __launch_bounds__(256) void bucket_scatter2(
    const unsigned int* __restrict__ part,
    const int* __restrict__ sbase,
    int* __restrict__ cnt,
    unsigned short* __restrict__ bucket,
    int* __restrict__ ovfn,
    long long* __restrict__ ovf)
{
    const int slice = blockIdx.x & 7;
    const int g     = blockIdx.x >> 3;
    const int nG    = (int)(gridDim.x >> 3);
    const int lo    = sbase[slice];
    const int hi    = sbase[slice + 1];
    const int m     = hi - lo;

    const int chunk = (m + nG - 1) / nG;
    const int e0 = lo + g * chunk;
    int e1 = e0 + chunk; if (e1 > hi) e1 = hi;

    for (int e = e0 + (int)threadIdx.x; e < e1; e += 256) {
        unsigned int pk = part[e];
        int d = (int)(pk >> 16);
        int s = (int)(pk & 0xffffu);
        int c = atomicAdd(&cnt[d], 1);
        if (c < CAP) {
            bucket[(size_t)d * CAP + c] = (unsigned short)s;
        } else {
            int o = atomicAdd(ovfn, 1);
            if (o < OVF_CAP) ovf[o] = ((long long)d << 32) | (unsigned int)s;
        }
    }
}

// ---------------------------------------------------------------------------
// K5 (fused gather_mean + gemm) — byte-exact R5-design (best measured:
// 172.3 total in the R8 pipeline). One 16-row tile per block, 256 threads =
// 4 waves, 4 nodes/wave. Scalar addressing (node/cnt/bucket wave-uniform ->
// s_load), full-wave coalesced rows (lane owns column pair {2l,2l+1}, no
// cross-lane reduce), 16-deep load batches, sentinel-padded buckets (index
// n = zero row) -> branchless batch 0, single wave-uniform deg>16 skip for
// batch 1. Means packed to LDS [16][68] u32; GEMM: wave w -> tiles 2w,2w+1.
// blockIdx&7 == slice keeps cnt/bucket reads XCD-affine with their writers.
// ---------------------------------------------------------------------------
__global__ __launch_bounds__(256) void gather_gemm(
    const int* __restrict__ cnt,
    const unsigned short* __restrict__ bucket,
    const int* __restrict__ ovfn,
    const long long* __restrict__ ovf,
    const unsigned short* __restrict__ hbf,
    const unsigned short* __restrict__ Be,
    const unsigned short* __restrict__ Bsf,
    const float* __restrict__ bias,
    float* __restrict__ out,
    int n, int nrt)
{
    __shared__ __align__(16) unsigned int wl[16 * 68];   // 4352 B

    const int t    = threadIdx.x;
    const int lane = t & 63;
    const int widu = __builtin_amdgcn_readfirstlane(t >> 6);   // uniform wave id
    const int slice = blockIdx.x & 7;
    const int g     = blockIdx.x >> 3;
    const int tLo = (int)(((long long)slice * nrt) >> 3);
    const int tHi = (int)(((long long)(slice + 1) * nrt) >> 3);
    const int tile = tLo + g;
    if (tile >= tHi) return;          // uniform across block

    const unsigned int* h32 = (const unsigned int*)hbf;   // 64 uints per row

    // ---- gather phase: 4 nodes per wave, full-wave coalesced rows ----
#pragma unroll
    for (int k = 0; k < 4; ++k) {
        const int mm   = widu * 4 + k;
        const int node = tile * 16 + mm;
        float ax = 0.f, ay = 0.f;
        int deg = 0;
        if (node < n) {                               // wave-uniform
            deg = cnt[node];                          // scalar load
            const unsigned short* bk = &bucket[(size_t)node * CAP];

            // batch 0: slots 0..15 (sentinel-padded -> always safe)
            {
                unsigned int v[16];
#pragma unroll
                for (int i = 0; i < 16; ++i) {
                    const unsigned int r = bk[i];     // SALU extract from s_load
                    v[i] = h32[(size_t)r * 64 + lane];
                }
#pragma unroll
                for (int i = 0; i < 16; ++i) {
                    ax += lo_f(v[i]); ay += hi_f(v[i]);
                }
            }
            // batch 1: slots 16..31 (wave-uniform skip)
            if (deg > 16) {
                unsigned int v[16];
#pragma unroll
                for (int i = 0; i < 16; ++i) {
                    const unsigned int r = bk[16 + i];
                    v[i] = h32[(size_t)r * 64 + lane];
                }
#pragma unroll
                for (int i = 0; i < 16; ++i) {
                    ax += lo_f(v[i]); ay += hi_f(v[i]);
                }
            }

            if (deg > CAP) {             // exact fallback; few nodes hit it
                int no = *ovfn; if (no > OVF_CAP) no = OVF_CAP;
                for (int o = 0; o < no; ++o) {
                    long long pk = ovf[o];
                    if ((int)(pk >> 32) == node) {
                        unsigned int x = h32[(size_t)(unsigned int)pk * 64 + lane];
                        ax += lo_f(x); ay += hi_f(x);
                    }
                }
            }
        }

        float sc = deg > 0 ? 1.0f / (float)deg : 0.f;
        // lane holds cols {2*lane, 2*lane+1}: word `lane` of node mm's row
        wl[mm * 68 + lane] = pack2(ax * sc, ay * sc);
    }
    __syncthreads();

    // ---- GEMM phase: 4 waves split the 8 column tiles (2 each) ----
    const int rr = lane & 15, qq = lane >> 4;
    const int row0 = tile * 16;

    bf16x8 ah[4], ag[4];
#pragma unroll
    for (int kc = 0; kc < 4; ++kc) {
        int gr = row0 + rr; if (gr > n - 1) gr = n - 1;
        ah[kc] = *(const bf16x8*)&hbf[(size_t)gr * N_HID + kc * 32 + qq * 8];
        // A-frag: row rr, u32 cols kc*16 + qq*4 .. +3 (padded stride 68)
        ag[kc] = *(const bf16x8*)&wl[rr * 68 + kc * 16 + qq * 4];
    }

    const int colb = lane & 15;
    const int rq   = (lane >> 4) * 4;

#pragma unroll
    for (int cti = 0; cti < 2; ++cti) {
        int ct = widu * 2 + cti;
        const bf16x8* BpS = (const bf16x8*)(Bsf + (size_t)ct * 2048);
        const bf16x8* BpE = (const bf16x8*)(Be  + (size_t)ct * 2048);
        f32x4 acc = {0.f, 0.f, 0.f, 0.f};
        acc = __builtin_amdgcn_mfma_f32_16x16x32_bf16(ah[0], BpS[lane],       acc, 0, 0, 0);
        acc = __builtin_amdgcn_mfma_f32_16x16x32_bf16(ah[1], BpS[64 + lane],  acc, 0, 0, 0);
        acc = __builtin_amdgcn_mfma_f32_16x16x32_bf16(ah[2], BpS[128 + lane], acc, 0, 0, 0);
        acc = __builtin_amdgcn_mfma_f32_16x16x32_bf16(ah[3], BpS[192 + lane], acc, 0, 0, 0);
        acc = __builtin_amdgcn_mfma_f32_16x16x32_bf16(ag[0], BpE[lane],       acc, 0, 0, 0);
        acc = __builtin_amdgcn_mfma_f32_16x16x32_bf16(ag[1], BpE[64 + lane],  acc, 0, 0, 0);
        acc = __builtin_amdgcn_mfma_f32_16x16x32_bf16(ag[2], BpE[128 + lane], acc, 0, 0, 0);
        acc = __builtin_amdgcn_mfma_f32_16x16x32_bf16(ag[3], BpE[192 + lane], acc, 0, 0, 0);

        int col = ct * 16 + colb;
        float bv = bias[col];
#pragma unroll
        for (int r = 0; r < 4; ++r) {
            int row = row0 + rq + r;
            if (row < n) out[(size_t)row * N_HID + col] = fmaxf(acc[r] + bv, 0.f);
        }
    }
}

// ---------------------------------------------------------------------------
extern "C" void kernel_launch(void* const* d_in, const int* in_sizes, int n_in,
                              void* d_out, int out_size, void* d_ws, size_t ws_size,
                              hipStream_t stream)
{
    const float* h   = (const float*)d_in[0];
    const int*   src = (const int*)d_in[1];
    const int*   dst = (const int*)d_in[2];
    const float* We  = (const float*)d_in[3];
    const float* Ws  = (const float*)d_in[4];
    const float* bs  = (const float*)d_in[5];
    float*       out = (float*)d_out;

    const int n   = in_sizes[0] / N_HID;    // 50000
    const int E   = in_sizes[1];            // 800000
    const int nrt = (n + 15) / 16;          // 3125 row tiles
    const float sln = (float)NSLICE / (float)n;
    const int total = n * N_HID;

    // workspace (~20 MB of the 256 MiB d_ws)
    unsigned short* hbf  = (unsigned short*)d_ws;             // (n+1)*128 bf16 (row n = zero sentinel)
    unsigned short* bucket = hbf + (size_t)(n + 1) * N_HID;   // n*CAP ushort (3.2 MB)
    unsigned short* Be  = bucket + (size_t)n * CAP;           // 8*2048
    unsigned short* Bs  = Be + 8 * 2048;                      // 8*2048
    int*  cnt  = (int*)(Bs + 8 * 2048);                       // n
    int*  ovfn = cnt + n;                                     // 1 (+pad)
    long long* ovf = (long long*)(ovfn + 8);                  // OVF_CAP
    int*  blockCnt  = (int*)(ovf + OVF_CAP);                  // PBLK*NSLICE
    int*  sbase     = blockCnt + PBLK * NSLICE;               // 9 (+pad)
    unsigned int* part = (unsigned int*)(sbase + 16);         // E u32 (3.2 MB)

    const unsigned int sent2 = (unsigned int)n | ((unsigned int)n << 16);
    const int castBlocks = (total + N_HID + 2047) / 2048;     // covers rows 0..n

    // fused gather+gemm grid: one tile per block, blockIdx&7 = slice
    const int maxTilesPerSlice = (nrt + NSLICE - 1) / NSLICE; // 391
    const int ggGrid = NSLICE * maxTilesPerSlice;             // 3128

    count_fragw_cast<<<PBLK + 16 + castBlocks, 256, 0, stream>>>(
        dst, blockCnt, cnt, ovfn, E, n, sln, We, Ws, Be, Bs, h, hbf, total,
        (unsigned int*)bucket, sent2);
    part_scan_scatter<<<PBLK, 256, 0, stream>>>(blockCnt, sbase, src, dst,
                                                part, E, n, sln);
    bucket_scatter2<<<2048, 256, 0, stream>>>(part, sbase, cnt, bucket, ovfn, ovf);
    gather_gemm<<<ggGrid, 256, 0, stream>>>(cnt, bucket, ovfn, ovf,
                                            hbf, Be, Bs, bs, out, n, nrt);
}